// Round 4
// baseline (51.049 us; speedup 1.0000x reference)
//
#include <hip/hip_runtime.h>

#define E_DIM 768

typedef __attribute__((ext_vector_type(8))) short bf16x8;
typedef __attribute__((ext_vector_type(4))) float f32x4;

__device__ __forceinline__ unsigned short f2bf(float f) {
    union { float f; unsigned int u; } v; v.f = f;
    unsigned int u = v.u;
    return (unsigned short)((u + 0x7FFFu + ((u >> 16) & 1u)) >> 16);
}
__device__ __forceinline__ float bfu_lo(unsigned int u) {
    union { unsigned int u; float f; } v; v.u = u << 16; return v.f;
}
__device__ __forceinline__ float bfu_hi(unsigned int u) {
    union { unsigned int u; float f; } v; v.u = u & 0xFFFF0000u; return v.f;
}
__device__ __forceinline__ float bfs(unsigned short s) {
    union { unsigned int u; float f; } v; v.u = ((unsigned int)s) << 16; return v.f;
}
__device__ __forceinline__ unsigned int cvt_pk_bf16(float lo, float hi) {
    unsigned int u;
    asm("v_cvt_pk_bf16_f32 %0, %1, %2" : "=v"(u) : "v"(lo), "v"(hi));
    return u;
}

// K1 (MFMA, 512 thr, grid 256): A = he_a @ Wa^T + ba ; C = he_p @ Wc^T + bc.
// Output bf16 shorts: per b: A_b = [i][512] at b*65536, C_b at +32768.
// Swizzle: mtile = loc&15 so bid%8 == mtile%8 -> same X slice stays on one XCD.
// Block 0 also zeroes score_acc[32] + counter (consumed by k_att_fused).
__global__ __launch_bounds__(512) void k_proj_mfma(
    const float* __restrict__ he_a, const float* __restrict__ Wa, const float* __restrict__ ba,
    const float* __restrict__ he_p, const float* __restrict__ Wc, const float* __restrict__ bc,
    unsigned short* __restrict__ dsts, float* __restrict__ score_acc,
    unsigned int* __restrict__ counter)
{
    __shared__ unsigned short Xs[128 * 40];   // [row][k], stride 40 bf16
    __shared__ unsigned short Wl[64 * 40];
    int t = threadIdx.x;
    int bid = blockIdx.x;
    if (bid == 0) {
        if (t < 32) score_acc[t] = 0.f;
        else if (t == 32) *counter = 0u;
    }
    int which = bid >> 7;
    int loc = bid & 127;
    int mbase = (loc & 15) * 128;   // row tile (16 tiles)
    int hbase = (loc >> 4) * 64;    // h tile (8 tiles)
    const float* Xg = which ? he_p : he_a;
    const float* Wg = which ? Wc : Wa;
    const float* bias = which ? bc : ba;
    int lane = t & 63, w = t >> 6;
    int wr = w >> 1, wc = w & 1;    // wave -> 32x32 sub-tile of the 128x64 block tile

    // staging slots: X rows 0..63 (slot0), 64..127 (slot1), W rows 0..63
    int xr0 = t >> 3,          xc0 = t & 7;
    int xr1 = (t + 512) >> 3,  xc1 = t & 7;
    int wrr = t >> 3,          wcc = t & 7;

    float4 p0 = *(const float4*)(Xg + (size_t)(mbase + xr0) * E_DIM + xc0 * 4);
    float4 p1 = *(const float4*)(Xg + (size_t)(mbase + xr1) * E_DIM + xc1 * 4);
    float4 p2 = *(const float4*)(Wg + (size_t)(hbase + wrr) * E_DIM + wcc * 4);

    f32x4 acc[2][2] = {};
    for (int kt = 0; kt < 24; ++kt) {
        __syncthreads();
        *(uint2*)&Xs[xr0 * 40 + xc0 * 4] =
            make_uint2(cvt_pk_bf16(p0.x, p0.y), cvt_pk_bf16(p0.z, p0.w));
        *(uint2*)&Xs[xr1 * 40 + xc1 * 4] =
            make_uint2(cvt_pk_bf16(p1.x, p1.y), cvt_pk_bf16(p1.z, p1.w));
        *(uint2*)&Wl[wrr * 40 + wcc * 4] =
            make_uint2(cvt_pk_bf16(p2.x, p2.y), cvt_pk_bf16(p2.z, p2.w));
        if (kt < 23) {
            int e0 = (kt + 1) * 32;
            p0 = *(const float4*)(Xg + (size_t)(mbase + xr0) * E_DIM + e0 + xc0 * 4);
            p1 = *(const float4*)(Xg + (size_t)(mbase + xr1) * E_DIM + e0 + xc1 * 4);
            p2 = *(const float4*)(Wg + (size_t)(hbase + wrr) * E_DIM + e0 + wcc * 4);
        }
        __syncthreads();
        int ar = lane & 15;
        int k0 = (lane >> 4) * 8;
        bf16x8 af[2], bfr[2];
#pragma unroll
        for (int mi = 0; mi < 2; ++mi)
            af[mi] = *(const bf16x8*)&Xs[(wr * 32 + mi * 16 + ar) * 40 + k0];
#pragma unroll
        for (int ni = 0; ni < 2; ++ni)
            bfr[ni] = *(const bf16x8*)&Wl[(wc * 32 + ni * 16 + ar) * 40 + k0];
#pragma unroll
        for (int mi = 0; mi < 2; ++mi)
#pragma unroll
            for (int ni = 0; ni < 2; ++ni)
                acc[mi][ni] = __builtin_amdgcn_mfma_f32_16x16x32_bf16(
                    af[mi], bfr[ni], acc[mi][ni], 0, 0, 0);
    }
#pragma unroll
    for (int ni = 0; ni < 2; ++ni) {
        int h = hbase + wc * 32 + ni * 16 + (lane & 15);
        float bv = bias[h];
#pragma unroll
        for (int mi = 0; mi < 2; ++mi) {
#pragma unroll
            for (int r = 0; r < 4; ++r) {
                int grow = mbase + wr * 32 + mi * 16 + (lane >> 4) * 4 + r;  // b*64+i
                int b = grow >> 6, i = grow & 63;
                float v = acc[mi][ni][r] + bv;
                dsts[(size_t)b * 65536 + (which ? 32768 : 0) + i * 512 + h] = f2bf(v);
            }
        }
    }
}

// K2 (fused, 512 thr, grid 256): one (b,k) per block (b = bid&31 -> same-b same XCD).
// No LDS staging: A/C fragments read straight from L2; Watt/Wsc folded into the
// A-fragment in registers (fp32 scale -> cvt_pk_bf16), then 16x16x32 MFMA.
// Waves: (rf = w&3) row-frag 16 rows, (jh = w>>2) 32-col half; acc 2x(S,G).
// Score: atomicAdd into score_acc[b]; last block (counter) computes loss.
__global__ __launch_bounds__(512) void k_att_fused(
    float* __restrict__ out, const unsigned short* __restrict__ src,
    const float* __restrict__ Watt, const float* __restrict__ Wsc,
    const float* __restrict__ he_neg, const float* __restrict__ bsc,
    float* __restrict__ score_acc, unsigned int* __restrict__ counter)
{
    __shared__ float red[8];
    __shared__ float sqv[32];
    __shared__ int lastflag;
    int t = threadIdx.x;
    int lane = t & 63, w = t >> 6;
    int rf = w & 3, jh = w >> 2;
    int b = blockIdx.x & 31, k = blockIdx.x >> 5;
    int l15 = lane & 15, lhi = lane >> 4;

    const unsigned short* Ab = src + (size_t)b * 65536;
    const unsigned short* Cb = Ab + 32768;
    const unsigned short* ap  = Ab + (size_t)(rf * 16 + l15) * 512 + lhi * 8;
    const unsigned short* cp0 = Cb + (size_t)(jh * 32 + l15) * 512 + lhi * 8;
    const unsigned short* cp1 = cp0 + 16 * 512;
    const float* wkbase = Watt + k * 512 + lhi * 8;
    const float* wgbase = Wsc  + k * 512 + lhi * 8;

    f32x4 accS[2] = {}, accG[2] = {};
#pragma unroll 2
    for (int ks = 0; ks < 16; ++ks) {
        int h = ks * 32;
        bf16x8 af  = *(const bf16x8*)(ap + h);
        bf16x8 cb0 = *(const bf16x8*)(cp0 + h);
        bf16x8 cb1 = *(const bf16x8*)(cp1 + h);
        float wkv[8], wgv[8];
        *(float4*)&wkv[0] = *(const float4*)(wkbase + h);
        *(float4*)&wkv[4] = *(const float4*)(wkbase + h + 4);
        *(float4*)&wgv[0] = *(const float4*)(wgbase + h);
        *(float4*)&wgv[4] = *(const float4*)(wgbase + h + 4);
        float a[8];
#pragma unroll
        for (int e = 0; e < 8; ++e) a[e] = bfs((unsigned short)af[e]);
        union { unsigned int u[4]; bf16x8 v; } ak, ag;
#pragma unroll
        for (int e2 = 0; e2 < 4; ++e2) {
            ak.u[e2] = cvt_pk_bf16(a[2 * e2] * wkv[2 * e2], a[2 * e2 + 1] * wkv[2 * e2 + 1]);
            ag.u[e2] = cvt_pk_bf16(a[2 * e2] * wgv[2 * e2], a[2 * e2 + 1] * wgv[2 * e2 + 1]);
        }
        accS[0] = __builtin_amdgcn_mfma_f32_16x16x32_bf16(ak.v, cb0, accS[0], 0, 0, 0);
        accS[1] = __builtin_amdgcn_mfma_f32_16x16x32_bf16(ak.v, cb1, accS[1], 0, 0, 0);
        accG[0] = __builtin_amdgcn_mfma_f32_16x16x32_bf16(ag.v, cb0, accG[0], 0, 0, 0);
        accG[1] = __builtin_amdgcn_mfma_f32_16x16x32_bf16(ag.v, cb1, accG[1], 0, 0, 0);
    }

    // block softmax over 4096 logits (batt cancels)
    float lmax = accS[0][0];
#pragma unroll
    for (int ni = 0; ni < 2; ++ni)
#pragma unroll
        for (int r = 0; r < 4; ++r) lmax = fmaxf(lmax, accS[ni][r]);
    float v = lmax;
#pragma unroll
    for (int off = 32; off > 0; off >>= 1) v = fmaxf(v, __shfl_xor(v, off));
    if (lane == 0) red[w] = v;
    __syncthreads();
    float M = red[0];
#pragma unroll
    for (int q = 1; q < 8; ++q) M = fmaxf(M, red[q]);
    __syncthreads();
    float ev[8];
    float lsum = 0.f;
#pragma unroll
    for (int ni = 0; ni < 2; ++ni)
#pragma unroll
        for (int r = 0; r < 4; ++r) {
            float e = __expf(accS[ni][r] - M);
            ev[ni * 4 + r] = e;
            lsum += e;
        }
    v = lsum;
#pragma unroll
    for (int off = 32; off > 0; off >>= 1) v += __shfl_xor(v, off);
    if (lane == 0) red[w] = v;
    __syncthreads();
    float Z = 0.f;
#pragma unroll
    for (int q = 0; q < 8; ++q) Z += red[q];
    float inv = 1.0f / Z;
    __syncthreads();

    // att write + score partial (G in the same lane/reg as att)
    float pacc = 0.f;
    float* attk = out + 33 + (size_t)b * 32768 + (size_t)k * 4096;
#pragma unroll
    for (int ni = 0; ni < 2; ++ni) {
        int j = jh * 32 + ni * 16 + l15;
#pragma unroll
        for (int r = 0; r < 4; ++r) {
            int i = rf * 16 + lhi * 4 + r;
            float av = ev[ni * 4 + r] * inv;
            attk[i * 64 + j] = av;
            pacc += av * accG[ni][r];
        }
    }
    v = pacc;
#pragma unroll
    for (int off = 32; off > 0; off >>= 1) v += __shfl_xor(v, off);
    if (lane == 0) red[w] = v;
    __syncthreads();
    if (t == 0) {
        float tot = 0.f;
#pragma unroll
        for (int q = 0; q < 8; ++q) tot += red[q];
        atomicAdd(&score_acc[b], tot);
        __threadfence();
        unsigned int done = atomicAdd(counter, 1u);
        lastflag = (done == 255u) ? 1 : 0;
    }
    __syncthreads();
    if (lastflag) {
        __threadfence();
        if (t < 32) {
            float s = atomicAdd(&score_acc[t], 0.0f) + bsc[0];  // device-scope read
            out[t] = s;
            float d = s - he_neg[t];
            sqv[t] = d * d;
        }
        __syncthreads();
        if (t == 0) {
            float l = 0.f;
            for (int q = 0; q < 32; ++q) l += sqv[q];
            out[32] = l * (1.0f / 32.0f);
        }
    }
}

// ---- fallback path (no workspace): VALU att + separate loss ----
__global__ __launch_bounds__(256) void k_att_valu8(
    float* __restrict__ out, const unsigned int* __restrict__ src,
    const float* __restrict__ Watt, const float* __restrict__ Wsc)
{
    __shared__ unsigned int Al[64 * 260];
    __shared__ unsigned int Cl[64 * 260];
    __shared__ float Wattl[512], Wscl[512];
    __shared__ float red[4];
    int t = threadIdx.x;
    int lane = t & 63, wave = t >> 6;
    int b = blockIdx.x;
    const unsigned int* srcb = src + (size_t)b * 32768;

    for (int s = t; s < 16384; s += 256) {
        int row = s >> 8, hp = s & 255;
        Al[row * 260 + hp] = srcb[s];
        Cl[row * 260 + hp] = srcb[16384 + s];
    }

    int i = t >> 2;
    int jb = (t & 3) * 16;
    float* attreg = out + 33 + (size_t)b * 32768;
    float blocktotal = 0.f;

    for (int k = 0; k < 8; ++k) {
        for (int s = t; s < 512; s += 256) {
            Wattl[s] = Watt[k * 512 + s];
            Wscl[s]  = Wsc[k * 512 + s];
        }
        __syncthreads();
        float sacc[16] = {}, gacc[16] = {};
        const unsigned int* Arow = &Al[i * 260];
        const unsigned int* Crow = &Cl[jb * 260];
        for (int hp = 0; hp < 256; hp += 2) {
            uint2 au = *(const uint2*)&Arow[hp];
            float a0 = bfu_lo(au.x), a1 = bfu_hi(au.x);
            float a2 = bfu_lo(au.y), a3 = bfu_hi(au.y);
            int h0 = hp * 2;
            float4 wk = *(const float4*)&Wattl[h0];
            float4 wg = *(const float4*)&Wscl[h0];
            float ak0 = a0 * wk.x, ak1 = a1 * wk.y, ak2 = a2 * wk.z, ak3 = a3 * wk.w;
            float ag0 = a0 * wg.x, ag1 = a1 * wg.y, ag2 = a2 * wg.z, ag3 = a3 * wg.w;
#pragma unroll
            for (int q = 0; q < 16; ++q) {
                uint2 cu = *(const uint2*)&Crow[q * 260 + hp];
                float c0 = bfu_lo(cu.x), c1 = bfu_hi(cu.x);
                float c2 = bfu_lo(cu.y), c3 = bfu_hi(cu.y);
                sacc[q] = fmaf(ak0, c0, sacc[q]); gacc[q] = fmaf(ag0, c0, gacc[q]);
                sacc[q] = fmaf(ak1, c1, sacc[q]); gacc[q] = fmaf(ag1, c1, gacc[q]);
                sacc[q] = fmaf(ak2, c2, sacc[q]); gacc[q] = fmaf(ag2, c2, gacc[q]);
                sacc[q] = fmaf(ak3, c3, sacc[q]); gacc[q] = fmaf(ag3, c3, gacc[q]);
            }
        }
        float lmax = sacc[0];
#pragma unroll
        for (int e = 1; e < 16; ++e) lmax = fmaxf(lmax, sacc[e]);
        float v = lmax;
#pragma unroll
        for (int off = 32; off > 0; off >>= 1) v = fmaxf(v, __shfl_xor(v, off));
        if (lane == 0) red[wave] = v;
        __syncthreads();
        float M = fmaxf(fmaxf(red[0], red[1]), fmaxf(red[2], red[3]));
        __syncthreads();
        float lsum = 0.f;
#pragma unroll
        for (int e = 0; e < 16; ++e) {
            sacc[e] = __expf(sacc[e] - M);
            lsum += sacc[e];
        }
        v = lsum;
#pragma unroll
        for (int off = 32; off > 0; off >>= 1) v += __shfl_xor(v, off);
        if (lane == 0) red[wave] = v;
        __syncthreads();
        float Z = red[0] + red[1] + red[2] + red[3];
        float inv = 1.0f / Z;
        __syncthreads();
        float pacc = 0.f;
        float* attk = attreg + k * 4096 + i * 64 + jb;
#pragma unroll
        for (int e = 0; e < 16; ++e) {
            float att = sacc[e] * inv;
            attk[e] = att;
            pacc += att * gacc[e];
        }
        v = pacc;
#pragma unroll
        for (int off = 32; off > 0; off >>= 1) v += __shfl_xor(v, off);
        if (lane == 0) red[wave] = v;
        __syncthreads();
        if (t == 0) blocktotal += red[0] + red[1] + red[2] + red[3];
        __syncthreads();
    }
    if (t == 0) out[b] = blocktotal;
}

__global__ __launch_bounds__(64) void k_loss(
    float* __restrict__ out, const float* __restrict__ he_neg,
    const float* __restrict__ bsc)
{
    __shared__ float sq[32];
    int t = threadIdx.x;
    if (t < 32) {
        float s = out[t] + bsc[0];
        out[t] = s;
        float d = s - he_neg[t];
        sq[t] = d * d;
    }
    __syncthreads();
    if (t == 0) {
        float l = 0.f;
        for (int i2 = 0; i2 < 32; ++i2) l += sq[i2];
        out[32] = l * (1.0f / 32.0f);
    }
}

extern "C" void kernel_launch(void* const* d_in, const int* in_sizes, int n_in,
                              void* d_out, int out_size, void* d_ws, size_t ws_size,
                              hipStream_t stream) {
    int iA = 0, iP = 1, iN = 2, iWa = 3, iBa = 4, iWc = 5, iBc = 6, iWatt = 7, iWsc = 9, iBsc = 10;
    if (!(in_sizes[0] == 1572864 && in_sizes[2] == 32)) {
        if (n_in == 11 && in_sizes[0] == 393216 && in_sizes[8] == 1572864) {
            iWa = 0; iWatt = 1; iWc = 2; iWsc = 3; iBa = 4; iBc = 6; iBsc = 7;
            iA = 8; iN = 9; iP = 10;
        }
    }
    const float* he_a  = (const float*)d_in[iA];
    const float* he_p  = (const float*)d_in[iP];
    const float* he_n  = (const float*)d_in[iN];
    const float* Wa    = (const float*)d_in[iWa];
    const float* ba    = (const float*)d_in[iBa];
    const float* Wc    = (const float*)d_in[iWc];
    const float* bc    = (const float*)d_in[iBc];
    const float* Watt  = (const float*)d_in[iWatt];
    const float* Wsc   = (const float*)d_in[iWsc];
    const float* bsc   = (const float*)d_in[iBsc];
    float* out = (float*)d_out;

    size_t need = ((size_t)4 << 20) + 256;   // A/C scratch (4MB) + score_acc + counter
    if (d_ws != nullptr && ws_size >= need) {
        unsigned short* wss = (unsigned short*)d_ws;
        float* score_acc = (float*)((char*)d_ws + ((size_t)4 << 20));
        unsigned int* counter = (unsigned int*)(score_acc + 32);
        k_proj_mfma<<<dim3(256), dim3(512), 0, stream>>>(
            he_a, Wa, ba, he_p, Wc, bc, wss, score_acc, counter);
        k_att_fused<<<dim3(256), dim3(512), 0, stream>>>(
            out, wss, Watt, Wsc, he_n, bsc, score_acc, counter);
    } else {
        // Fallback: pack A/C into the att region of d_out (race-free: one block per b).
        unsigned short* region = (unsigned short*)(out + 33);
        static float s_dummy[33];  // never used on this path's device? keep layout simple
        (void)s_dummy;
        // zero-scratch not available: use old 3-kernel path without ws.
        // k_proj needs score_acc/counter pointers; pass out-region scratch (b=0 unused rows?).
        // Simplest: reuse out+33 tail? Not safe. Use a null-guarded variant: grid!=0 check.
        // We pass score_acc=out (scores) and a counter inside out[32]? Avoid: launch with
        // pointers into d_out beyond att region is not possible. Instead: small static ws-free
        // path: k_proj writes A/C only (score_acc=nullptr skip), then VALU att + loss.
        k_proj_mfma<<<dim3(256), dim3(512), 0, stream>>>(
            he_a, Wa, ba, he_p, Wc, bc, region, (float*)(out), (unsigned int*)(out + 32));
        // NOTE: k_proj zeroes out[0..32]; k_att_valu8 then overwrites scores, k_loss adds bias.
        k_att_valu8<<<dim3(32), dim3(256), 0, stream>>>(out, (unsigned int*)region, Watt, Wsc);
        k_loss<<<dim3(1), dim3(64), 0, stream>>>(out, he_n, bsc);
    }
}

// Round 5
// 49.002 us; speedup vs baseline: 1.0418x; 1.0418x over previous
//
#include <hip/hip_runtime.h>

#define E_DIM 768

typedef __attribute__((ext_vector_type(8))) short bf16x8;
typedef __attribute__((ext_vector_type(4))) float f32x4;

__device__ __forceinline__ unsigned short f2bf(float f) {
    union { float f; unsigned int u; } v; v.f = f;
    unsigned int u = v.u;
    return (unsigned short)((u + 0x7FFFu + ((u >> 16) & 1u)) >> 16);
}
__device__ __forceinline__ float bfu_lo(unsigned int u) {
    union { unsigned int u; float f; } v; v.u = u << 16; return v.f;
}
__device__ __forceinline__ float bfu_hi(unsigned int u) {
    union { unsigned int u; float f; } v; v.u = u & 0xFFFF0000u; return v.f;
}
__device__ __forceinline__ float bfs(unsigned short s) {
    union { unsigned int u; float f; } v; v.u = ((unsigned int)s) << 16; return v.f;
}
__device__ __forceinline__ unsigned int cvt_pk_bf16(float lo, float hi) {
    unsigned int u;
    asm("v_cvt_pk_bf16_f32 %0, %1, %2" : "=v"(u) : "v"(lo), "v"(hi));
    return u;
}

// K1 (MFMA, 256 thr, grid 256): A = he_a @ Wa^T + ba ; C = he_p @ Wc^T + bc.
// Output bf16 shorts per b: A_b = [i][512] at b*65536, C_b at +32768.
// Swizzle: mtile = loc&15 -> bid%8 = m%8, so ALL writes of b's data land on
// XCD ((b>>1)%8) (X-tile reuse also same-XCD). k_att reads from that same XCD.
__global__ __launch_bounds__(256) void k_proj_mfma(
    const float* __restrict__ he_a, const float* __restrict__ Wa, const float* __restrict__ ba,
    const float* __restrict__ he_p, const float* __restrict__ Wc, const float* __restrict__ bc,
    unsigned short* __restrict__ dsts, float* __restrict__ score_acc,
    unsigned int* __restrict__ counter)
{
    __shared__ unsigned short Xs[128 * 40];   // [row][k], stride 40 bf16
    __shared__ unsigned short Wl[64 * 40];
    int bid = blockIdx.x;
    int t = threadIdx.x;
    if (bid == 0) {
        if (t < 32) score_acc[t] = 0.f;
        else if (t == 32) *counter = 0u;
    }
    int which = bid >> 7;
    int loc = bid & 127;
    int mbase = (loc & 15) * 128;   // 16 row tiles of 128 -> XCD = (loc&15)%8
    int hbase = (loc >> 4) * 64;    // 8 h tiles
    const float* Xg = which ? he_p : he_a;
    const float* Wg = which ? Wc : Wa;
    const float* bias = which ? bc : ba;
    int lane = t & 63, w = t >> 6;
    int wr = w >> 1, wc = w & 1;    // wave -> 64x32 sub-tile

    float4 xr4[4];
    float4 wr4[2];
#pragma unroll
    for (int it = 0; it < 4; ++it) {
        int idx = t + it * 256; int row = idx >> 3, c4 = idx & 7;
        xr4[it] = *(const float4*)(Xg + (size_t)(mbase + row) * E_DIM + c4 * 4);
    }
#pragma unroll
    for (int it = 0; it < 2; ++it) {
        int idx = t + it * 256; int row = idx >> 3, c4 = idx & 7;
        wr4[it] = *(const float4*)(Wg + (size_t)(hbase + row) * E_DIM + c4 * 4);
    }

    f32x4 acc[4][2] = {};
    for (int kt = 0; kt < 24; ++kt) {
        __syncthreads();
#pragma unroll
        for (int it = 0; it < 4; ++it) {
            int idx = t + it * 256; int row = idx >> 3, c4 = idx & 7;
            uint2 u = make_uint2(cvt_pk_bf16(xr4[it].x, xr4[it].y),
                                 cvt_pk_bf16(xr4[it].z, xr4[it].w));
            *(uint2*)&Xs[row * 40 + c4 * 4] = u;
        }
#pragma unroll
        for (int it = 0; it < 2; ++it) {
            int idx = t + it * 256; int row = idx >> 3, c4 = idx & 7;
            uint2 u = make_uint2(cvt_pk_bf16(wr4[it].x, wr4[it].y),
                                 cvt_pk_bf16(wr4[it].z, wr4[it].w));
            *(uint2*)&Wl[row * 40 + c4 * 4] = u;
        }
        if (kt < 23) {
            int e0 = (kt + 1) * 32;
#pragma unroll
            for (int it = 0; it < 4; ++it) {
                int idx = t + it * 256; int row = idx >> 3, c4 = idx & 7;
                xr4[it] = *(const float4*)(Xg + (size_t)(mbase + row) * E_DIM + e0 + c4 * 4);
            }
#pragma unroll
            for (int it = 0; it < 2; ++it) {
                int idx = t + it * 256; int row = idx >> 3, c4 = idx & 7;
                wr4[it] = *(const float4*)(Wg + (size_t)(hbase + row) * E_DIM + e0 + c4 * 4);
            }
        }
        __syncthreads();
        int ar = lane & 15;
        int k0 = (lane >> 4) * 8;
        bf16x8 af[4], bfr[2];
#pragma unroll
        for (int mi = 0; mi < 4; ++mi)
            af[mi] = *(const bf16x8*)&Xs[(wr * 64 + mi * 16 + ar) * 40 + k0];
#pragma unroll
        for (int ni = 0; ni < 2; ++ni)
            bfr[ni] = *(const bf16x8*)&Wl[(wc * 32 + ni * 16 + ar) * 40 + k0];
#pragma unroll
        for (int mi = 0; mi < 4; ++mi)
#pragma unroll
            for (int ni = 0; ni < 2; ++ni)
                acc[mi][ni] = __builtin_amdgcn_mfma_f32_16x16x32_bf16(
                    af[mi], bfr[ni], acc[mi][ni], 0, 0, 0);
    }
#pragma unroll
    for (int ni = 0; ni < 2; ++ni) {
        int h = hbase + wc * 32 + ni * 16 + (lane & 15);
        float bv = bias[h];
#pragma unroll
        for (int mi = 0; mi < 4; ++mi) {
#pragma unroll
            for (int r = 0; r < 4; ++r) {
                int grow = mbase + wr * 64 + mi * 16 + (lane >> 4) * 4 + r;  // b*64+i
                int b = grow >> 6, i = grow & 63;
                float v = acc[mi][ni][r] + bv;
                dsts[(size_t)b * 65536 + (which ? 32768 : 0) + i * 512 + h] = f2bf(v);
            }
        }
    }
}

// K2 (fused, 512 thr, grid 256): one (b,k) per block.
// XCD-matched remap: x=bid&7, s=bid>>3, b = 2x+(s&1)+16*((s>>1)&1), k = s>>2
//   -> (b>>1)%8 == bid%8 == XCD where k_proj wrote A_b/C_b (same-XCD L2 hits).
// A/C read direct from L2; Watt/Wsc folded into A-frag in registers; explicit
// double-buffered register prefetch over the 16 ks steps.
__global__ __launch_bounds__(512) void k_att_fused(
    float* __restrict__ out, const unsigned short* __restrict__ src,
    const float* __restrict__ Watt, const float* __restrict__ Wsc,
    const float* __restrict__ he_neg, const float* __restrict__ bsc,
    float* __restrict__ score_acc, unsigned int* __restrict__ counter)
{
    __shared__ float red[8];
    __shared__ float sqv[32];
    __shared__ int lastflag;
    int t = threadIdx.x;
    int lane = t & 63, w = t >> 6;
    int rf = w & 3, jh = w >> 2;
    int bid = blockIdx.x;
    int x = bid & 7, s = bid >> 3;
    int b = 2 * x + (s & 1) + 16 * ((s >> 1) & 1);
    int k = s >> 2;
    int l15 = lane & 15, lhi = lane >> 4;

    const unsigned short* Ab = src + (size_t)b * 65536;
    const unsigned short* Cb = Ab + 32768;
    const unsigned short* ap  = Ab + (size_t)(rf * 16 + l15) * 512 + lhi * 8;
    const unsigned short* cp0 = Cb + (size_t)(jh * 32 + l15) * 512 + lhi * 8;
    const unsigned short* cp1 = cp0 + 16 * 512;
    const float* wkb = Watt + k * 512 + lhi * 8;
    const float* wgb = Wsc  + k * 512 + lhi * 8;

    bf16x8 af_[2], c0_[2], c1_[2];
    float4 wk0_[2], wk1_[2], wg0_[2], wg1_[2];
    af_[0]  = *(const bf16x8*)(ap);
    c0_[0]  = *(const bf16x8*)(cp0);
    c1_[0]  = *(const bf16x8*)(cp1);
    wk0_[0] = *(const float4*)(wkb);
    wk1_[0] = *(const float4*)(wkb + 4);
    wg0_[0] = *(const float4*)(wgb);
    wg1_[0] = *(const float4*)(wgb + 4);

    f32x4 accS[2] = {}, accG[2] = {};
#pragma unroll
    for (int ks = 0; ks < 16; ++ks) {
        int cur = ks & 1, nxt = cur ^ 1;
        if (ks < 15) {
            int h = (ks + 1) * 32;
            af_[nxt]  = *(const bf16x8*)(ap + h);
            c0_[nxt]  = *(const bf16x8*)(cp0 + h);
            c1_[nxt]  = *(const bf16x8*)(cp1 + h);
            wk0_[nxt] = *(const float4*)(wkb + h);
            wk1_[nxt] = *(const float4*)(wkb + h + 4);
            wg0_[nxt] = *(const float4*)(wgb + h);
            wg1_[nxt] = *(const float4*)(wgb + h + 4);
        }
        float a[8];
#pragma unroll
        for (int e = 0; e < 8; ++e) a[e] = bfs((unsigned short)af_[cur][e]);
        float wkv[8], wgv[8];
        *(float4*)&wkv[0] = wk0_[cur]; *(float4*)&wkv[4] = wk1_[cur];
        *(float4*)&wgv[0] = wg0_[cur]; *(float4*)&wgv[4] = wg1_[cur];
        union { unsigned int u[4]; bf16x8 v; } ak, ag;
#pragma unroll
        for (int e2 = 0; e2 < 4; ++e2) {
            ak.u[e2] = cvt_pk_bf16(a[2 * e2] * wkv[2 * e2], a[2 * e2 + 1] * wkv[2 * e2 + 1]);
            ag.u[e2] = cvt_pk_bf16(a[2 * e2] * wgv[2 * e2], a[2 * e2 + 1] * wgv[2 * e2 + 1]);
        }
        accS[0] = __builtin_amdgcn_mfma_f32_16x16x32_bf16(ak.v, c0_[cur], accS[0], 0, 0, 0);
        accS[1] = __builtin_amdgcn_mfma_f32_16x16x32_bf16(ak.v, c1_[cur], accS[1], 0, 0, 0);
        accG[0] = __builtin_amdgcn_mfma_f32_16x16x32_bf16(ag.v, c0_[cur], accG[0], 0, 0, 0);
        accG[1] = __builtin_amdgcn_mfma_f32_16x16x32_bf16(ag.v, c1_[cur], accG[1], 0, 0, 0);
    }

    // block softmax over 4096 logits (batt cancels)
    float lmax = accS[0][0];
#pragma unroll
    for (int ni = 0; ni < 2; ++ni)
#pragma unroll
        for (int r = 0; r < 4; ++r) lmax = fmaxf(lmax, accS[ni][r]);
    float v = lmax;
#pragma unroll
    for (int off = 32; off > 0; off >>= 1) v = fmaxf(v, __shfl_xor(v, off));
    if (lane == 0) red[w] = v;
    __syncthreads();
    float M = red[0];
#pragma unroll
    for (int q = 1; q < 8; ++q) M = fmaxf(M, red[q]);
    __syncthreads();
    float ev[8];
    float lsum = 0.f;
#pragma unroll
    for (int ni = 0; ni < 2; ++ni)
#pragma unroll
        for (int r = 0; r < 4; ++r) {
            float e = __expf(accS[ni][r] - M);
            ev[ni * 4 + r] = e;
            lsum += e;
        }
    v = lsum;
#pragma unroll
    for (int off = 32; off > 0; off >>= 1) v += __shfl_xor(v, off);
    if (lane == 0) red[w] = v;
    __syncthreads();
    float Z = 0.f;
#pragma unroll
    for (int q = 0; q < 8; ++q) Z += red[q];
    float inv = 1.0f / Z;
    __syncthreads();

    // att write + score partial
    float pacc = 0.f;
    float* attk = out + 33 + (size_t)b * 32768 + (size_t)k * 4096;
#pragma unroll
    for (int ni = 0; ni < 2; ++ni) {
        int j = jh * 32 + ni * 16 + l15;
#pragma unroll
        for (int r = 0; r < 4; ++r) {
            int i = rf * 16 + lhi * 4 + r;
            float av = ev[ni * 4 + r] * inv;
            attk[i * 64 + j] = av;
            pacc += av * accG[ni][r];
        }
    }
    v = pacc;
#pragma unroll
    for (int off = 32; off > 0; off >>= 1) v += __shfl_xor(v, off);
    if (lane == 0) red[w] = v;
    __syncthreads();
    if (t == 0) {
        float tot = 0.f;
#pragma unroll
        for (int q = 0; q < 8; ++q) tot += red[q];
        atomicAdd(&score_acc[b], tot);
        __threadfence();
        unsigned int done = atomicAdd(counter, 1u);
        lastflag = (done == 255u) ? 1 : 0;
    }
    __syncthreads();
    if (lastflag) {
        __threadfence();
        if (t < 32) {
            float sc = atomicAdd(&score_acc[t], 0.0f) + bsc[0];  // device-scope read
            out[t] = sc;
            float d = sc - he_neg[t];
            sqv[t] = d * d;
        }
        __syncthreads();
        if (t == 0) {
            float l = 0.f;
            for (int q = 0; q < 32; ++q) l += sqv[q];
            out[32] = l * (1.0f / 32.0f);
        }
    }
}

// ---- fallback path (no workspace): VALU att + separate loss ----
__global__ __launch_bounds__(256) void k_att_valu8(
    float* __restrict__ out, const unsigned int* __restrict__ src,
    const float* __restrict__ Watt, const float* __restrict__ Wsc)
{
    __shared__ unsigned int Al[64 * 260];
    __shared__ unsigned int Cl[64 * 260];
    __shared__ float Wattl[512], Wscl[512];
    __shared__ float red[4];
    int t = threadIdx.x;
    int lane = t & 63, wave = t >> 6;
    int b = blockIdx.x;
    const unsigned int* srcb = src + (size_t)b * 32768;

    for (int s = t; s < 16384; s += 256) {
        int row = s >> 8, hp = s & 255;
        Al[row * 260 + hp] = srcb[s];
        Cl[row * 260 + hp] = srcb[16384 + s];
    }

    int i = t >> 2;
    int jb = (t & 3) * 16;
    float* attreg = out + 33 + (size_t)b * 32768;
    float blocktotal = 0.f;

    for (int k = 0; k < 8; ++k) {
        for (int s = t; s < 512; s += 256) {
            Wattl[s] = Watt[k * 512 + s];
            Wscl[s]  = Wsc[k * 512 + s];
        }
        __syncthreads();
        float sacc[16] = {}, gacc[16] = {};
        const unsigned int* Arow = &Al[i * 260];
        const unsigned int* Crow = &Cl[jb * 260];
        for (int hp = 0; hp < 256; hp += 2) {
            uint2 au = *(const uint2*)&Arow[hp];
            float a0 = bfu_lo(au.x), a1 = bfu_hi(au.x);
            float a2 = bfu_lo(au.y), a3 = bfu_hi(au.y);
            int h0 = hp * 2;
            float4 wk = *(const float4*)&Wattl[h0];
            float4 wg = *(const float4*)&Wscl[h0];
            float ak0 = a0 * wk.x, ak1 = a1 * wk.y, ak2 = a2 * wk.z, ak3 = a3 * wk.w;
            float ag0 = a0 * wg.x, ag1 = a1 * wg.y, ag2 = a2 * wg.z, ag3 = a3 * wg.w;
#pragma unroll
            for (int q = 0; q < 16; ++q) {
                uint2 cu = *(const uint2*)&Crow[q * 260 + hp];
                float c0 = bfu_lo(cu.x), c1 = bfu_hi(cu.x);
                float c2 = bfu_lo(cu.y), c3 = bfu_hi(cu.y);
                sacc[q] = fmaf(ak0, c0, sacc[q]); gacc[q] = fmaf(ag0, c0, gacc[q]);
                sacc[q] = fmaf(ak1, c1, sacc[q]); gacc[q] = fmaf(ag1, c1, gacc[q]);
                sacc[q] = fmaf(ak2, c2, sacc[q]); gacc[q] = fmaf(ag2, c2, gacc[q]);
                sacc[q] = fmaf(ak3, c3, sacc[q]); gacc[q] = fmaf(ag3, c3, gacc[q]);
            }
        }
        float lmax = sacc[0];
#pragma unroll
        for (int e = 1; e < 16; ++e) lmax = fmaxf(lmax, sacc[e]);
        float v = lmax;
#pragma unroll
        for (int off = 32; off > 0; off >>= 1) v = fmaxf(v, __shfl_xor(v, off));
        if (lane == 0) red[wave] = v;
        __syncthreads();
        float M = fmaxf(fmaxf(red[0], red[1]), fmaxf(red[2], red[3]));
        __syncthreads();
        float lsum = 0.f;
#pragma unroll
        for (int e = 0; e < 16; ++e) {
            sacc[e] = __expf(sacc[e] - M);
            lsum += sacc[e];
        }
        v = lsum;
#pragma unroll
        for (int off = 32; off > 0; off >>= 1) v += __shfl_xor(v, off);
        if (lane == 0) red[wave] = v;
        __syncthreads();
        float Z = red[0] + red[1] + red[2] + red[3];
        float inv = 1.0f / Z;
        __syncthreads();
        float pacc = 0.f;
        float* attk = attreg + k * 4096 + i * 64 + jb;
#pragma unroll
        for (int e = 0; e < 16; ++e) {
            float att = sacc[e] * inv;
            attk[e] = att;
            pacc += att * gacc[e];
        }
        v = pacc;
#pragma unroll
        for (int off = 32; off > 0; off >>= 1) v += __shfl_xor(v, off);
        if (lane == 0) red[wave] = v;
        __syncthreads();
        if (t == 0) blocktotal += red[0] + red[1] + red[2] + red[3];
        __syncthreads();
    }
    if (t == 0) out[b] = blocktotal;
}

__global__ __launch_bounds__(64) void k_loss(
    float* __restrict__ out, const float* __restrict__ he_neg,
    const float* __restrict__ bsc)
{
    __shared__ float sq[32];
    int t = threadIdx.x;
    if (t < 32) {
        float s = out[t] + bsc[0];
        out[t] = s;
        float d = s - he_neg[t];
        sq[t] = d * d;
    }
    __syncthreads();
    if (t == 0) {
        float l = 0.f;
        for (int i2 = 0; i2 < 32; ++i2) l += sq[i2];
        out[32] = l * (1.0f / 32.0f);
    }
}

extern "C" void kernel_launch(void* const* d_in, const int* in_sizes, int n_in,
                              void* d_out, int out_size, void* d_ws, size_t ws_size,
                              hipStream_t stream) {
    int iA = 0, iP = 1, iN = 2, iWa = 3, iBa = 4, iWc = 5, iBc = 6, iWatt = 7, iWsc = 9, iBsc = 10;
    if (!(in_sizes[0] == 1572864 && in_sizes[2] == 32)) {
        if (n_in == 11 && in_sizes[0] == 393216 && in_sizes[8] == 1572864) {
            iWa = 0; iWatt = 1; iWc = 2; iWsc = 3; iBa = 4; iBc = 6; iBsc = 7;
            iA = 8; iN = 9; iP = 10;
        }
    }
    const float* he_a  = (const float*)d_in[iA];
    const float* he_p  = (const float*)d_in[iP];
    const float* he_n  = (const float*)d_in[iN];
    const float* Wa    = (const float*)d_in[iWa];
    const float* ba    = (const float*)d_in[iBa];
    const float* Wc    = (const float*)d_in[iWc];
    const float* bc    = (const float*)d_in[iBc];
    const float* Watt  = (const float*)d_in[iWatt];
    const float* Wsc   = (const float*)d_in[iWsc];
    const float* bsc   = (const float*)d_in[iBsc];
    float* out = (float*)d_out;

    size_t need = ((size_t)4 << 20) + 256;   // A/C scratch (4MB) + score_acc + counter
    if (d_ws != nullptr && ws_size >= need) {
        unsigned short* wss = (unsigned short*)d_ws;
        float* score_acc = (float*)((char*)d_ws + ((size_t)4 << 20));
        unsigned int* counter = (unsigned int*)(score_acc + 32);
        k_proj_mfma<<<dim3(256), dim3(256), 0, stream>>>(
            he_a, Wa, ba, he_p, Wc, bc, wss, score_acc, counter);
        k_att_fused<<<dim3(256), dim3(512), 0, stream>>>(
            out, wss, Watt, Wsc, he_n, bsc, score_acc, counter);
    } else {
        // Fallback: pack A/C into the att region of d_out (race-free: one block per b).
        unsigned short* region = (unsigned short*)(out + 33);
        k_proj_mfma<<<dim3(256), dim3(256), 0, stream>>>(
            he_a, Wa, ba, he_p, Wc, bc, region, (float*)(out), (unsigned int*)(out + 32));
        k_att_valu8<<<dim3(32), dim3(256), 0, stream>>>(out, (unsigned int*)region, Watt, Wsc);
        k_loss<<<dim3(1), dim3(64), 0, stream>>>(out, he_n, bsc);
    }
}